// Round 7
// baseline (253.617 us; speedup 1.0000x reference)
//
#include <hip/hip_runtime.h>

constexpr int Bn = 4096;
constexpr int Dn = 256;
constexpr int Sn = 256;
constexpr int NITEMS = 100000;
constexpr int NBLK_SCAN = (NITEMS + 255) / 256;   // 391

// ---------------------------------------------------------------------------
// feat_hist: f = uf_cat @ W^T + bias, split-K=2 (grid 512, 2 blocks/CU).
// fout pre-zeroed; each half atomicAdds its partial (2 commutative fp32
// contributions -> deterministic). kh==0 blocks also do the item histogram.
// ---------------------------------------------------------------------------
__global__ __launch_bounds__(256) void feat_hist(
    const float* __restrict__ uf, const float* __restrict__ priv,
    const float* __restrict__ W,  const float* __restrict__ bias,
    const int* __restrict__ need_replace, const int* __restrict__ user_sample_items,
    float* __restrict__ fout, int* __restrict__ cnt) {
  __shared__ float A_s[32][68];
  __shared__ float B_s[32][68];
  const int bid = blockIdx.x;
  const int kh  = bid >> 8;          // 0 or 1: K half
  const int sb  = bid & 255;
  const int t   = threadIdx.x;

  if (kh == 0 && cnt != nullptr) {
#pragma unroll
    for (int it = 0; it < 16; ++it) {
      const int b = sb * 16 + it;
      const int uid  = need_replace[b * 2];
      const int item = user_sample_items[(size_t)uid * Sn + t];
      atomicAdd(&cnt[item], 1);
    }
  }

  const int m0 = (sb >> 2) * 64;
  const int n0 = (sb & 3) * 64;
  const int tx = t & 15, ty = t >> 4;
  const int c0 = kh * 8, c1 = c0 + 8;

  float acc[4][4];
#pragma unroll
  for (int i = 0; i < 4; ++i)
#pragma unroll
    for (int j = 0; j < 4; ++j) acc[i][j] = 0.f;

  float ra[8], rb[8];
#pragma unroll
  for (int p = 0; p < 8; ++p) {
    const int e = t + p * 256, kk = e & 31, m = e >> 5;
    ra[p] = uf[(size_t)(m0 + m) * 512 + c0 * 32 + kk];
    rb[p] = W[(size_t)(n0 + m) * 513 + c0 * 32 + kk];
  }

  for (int c = c0; c < c1; ++c) {
#pragma unroll
    for (int p = 0; p < 8; ++p) {
      const int e = t + p * 256, kk = e & 31, m = e >> 5;
      A_s[kk][m] = ra[p];
      B_s[kk][m] = rb[p];
    }
    __syncthreads();
    if (c + 1 < c1) {
      const int k0 = (c + 1) * 32;
#pragma unroll
      for (int p = 0; p < 8; ++p) {
        const int e = t + p * 256, kk = e & 31, m = e >> 5;
        ra[p] = uf[(size_t)(m0 + m) * 512 + k0 + kk];
        rb[p] = W[(size_t)(n0 + m) * 513 + k0 + kk];
      }
    }
#pragma unroll
    for (int kk = 0; kk < 32; ++kk) {
      const float4 a4 = *(const float4*)&A_s[kk][ty * 4];
      const float4 b4 = *(const float4*)&B_s[kk][tx * 4];
      const float av[4] = {a4.x, a4.y, a4.z, a4.w};
      const float bv[4] = {b4.x, b4.y, b4.z, b4.w};
#pragma unroll
      for (int i = 0; i < 4; ++i)
#pragma unroll
        for (int j = 0; j < 4; ++j) acc[i][j] = fmaf(av[i], bv[j], acc[i][j]);
    }
    __syncthreads();
  }

  if (kh == 1) {      // k = 512 tail: privacy column
    float av[4], bv[4];
#pragma unroll
    for (int i = 0; i < 4; ++i) av[i] = priv[m0 + ty * 4 + i];
#pragma unroll
    for (int j = 0; j < 4; ++j) bv[j] = W[(size_t)(n0 + tx * 4 + j) * 513 + 512];
#pragma unroll
    for (int i = 0; i < 4; ++i)
#pragma unroll
      for (int j = 0; j < 4; ++j) acc[i][j] = fmaf(av[i], bv[j], acc[i][j]);
  } else {            // bias added once, by the kh==0 half
    const float4 bb = *(const float4*)&bias[n0 + tx * 4];
#pragma unroll
    for (int i = 0; i < 4; ++i) {
      acc[i][0] += bb.x; acc[i][1] += bb.y;
      acc[i][2] += bb.z; acc[i][3] += bb.w;
    }
  }

#pragma unroll
  for (int i = 0; i < 4; ++i)
#pragma unroll
    for (int j = 0; j < 4; ++j)
      atomicAdd(&fout[(size_t)(m0 + ty * 4 + i) * Dn + n0 + tx * 4 + j], acc[i][j]);
}

// ---------------------------------------------------------------------------
// scan_a: block-local exclusive scan of cnt + per-block sums
// ---------------------------------------------------------------------------
__global__ __launch_bounds__(256) void scan_a(const int* __restrict__ cnt,
                                              int* __restrict__ offsets,
                                              int* __restrict__ blocksum) {
  __shared__ int s[256];
  const int tid = threadIdx.x;
  const int i = blockIdx.x * 256 + tid;
  const int v = (i < NITEMS) ? cnt[i] : 0;
  int x = v;
  s[tid] = x;
  __syncthreads();
  for (int d = 1; d < 256; d <<= 1) {
    const int add = (tid >= d) ? s[tid - d] : 0;
    __syncthreads();
    x += add;
    s[tid] = x;
    __syncthreads();
  }
  if (i < NITEMS) offsets[i] = x - v;
  if (tid == 255) blocksum[blockIdx.x] = x;
}

// ---------------------------------------------------------------------------
// scan_bc: block j sums blocksum[0..j) itself, finalizes offsets + cursor.
// ---------------------------------------------------------------------------
__global__ __launch_bounds__(256) void scan_bc(const int* __restrict__ blocksum,
                                               int* __restrict__ offsets,
                                               int* __restrict__ cursor) {
  __shared__ int red[4];
  const int tid = threadIdx.x, lane = tid & 63, w = tid >> 6;
  const int j = blockIdx.x;
  int part = 0;
  for (int i = tid; i < j; i += 256) part += blocksum[i];
#pragma unroll
  for (int off = 32; off; off >>= 1) part += __shfl_xor(part, off, 64);
  if (lane == 0) red[w] = part;
  __syncthreads();
  const int prefix = red[0] + red[1] + red[2] + red[3];
  const int i = j * 256 + tid;
  if (i < NITEMS) {
    const int o = offsets[i] + prefix;
    offsets[i] = o;
    cursor[i]  = o;
  }
}

// ---------------------------------------------------------------------------
// scatter: emit (cid, item) pairs grouped by item
// ---------------------------------------------------------------------------
__global__ __launch_bounds__(256) void scatter_kernel(
    const int* __restrict__ need_replace, const int* __restrict__ user_sample_items,
    int* __restrict__ cursor, int2* __restrict__ pairs) {
  const int b = blockIdx.x, t = threadIdx.x;
  const int uid  = need_replace[b * 2];
  const int item = user_sample_items[(size_t)uid * Sn + t];
  const int pos  = atomicAdd(&cursor[item], 1);
  pairs[pos] = make_int2(b * Sn + t, item);
}

// ---------------------------------------------------------------------------
// score_runs: block owns 256 item-sorted pairs; distinct item rows staged
// once in LDS (CROWS=32 batches -> 37 KB LDS -> 4 blocks/CU); rows padded
// +4 floats (bank rotation 4/slot -> conflict-free). 8-lane group per pair:
// f-row streamed (contiguous 128B/group-instr), item row from LDS.
// ---------------------------------------------------------------------------
constexpr int CH    = 256;
constexpr int CROWS = 32;
constexpr int RP    = Dn + 4;

__global__ __launch_bounds__(256) void score_runs(
    const float* __restrict__ all_items, const float* __restrict__ f,
    const int2* __restrict__ pairs, float* __restrict__ scores) {
  __shared__ float rows[CROWS][RP];
  __shared__ int cid_s[CH];
  __shared__ int item_s[CH];
  __shared__ int slot_s[CH];
  __shared__ int head_s[CH + 1];
  __shared__ int wsum[4];

  const int t = threadIdx.x, lane = t & 63, w = t >> 6;

  const int2 pr = pairs[(size_t)blockIdx.x * CH + t];
  cid_s[t]  = pr.x;
  item_s[t] = pr.y;
  __syncthreads();

  const int h = (t == 0) ? 1 : (item_s[t] != item_s[t - 1] ? 1 : 0);
  const unsigned long long mask = __ballot(h != 0);
  const int wc  = __popcll(mask);
  const int pre = __popcll(mask & ((1ull << lane) - 1ull));
  if (lane == 0) wsum[w] = wc;
  __syncthreads();
  int off0 = 0;
  for (int i = 0; i < w; ++i) off0 += wsum[i];
  const int k = wsum[0] + wsum[1] + wsum[2] + wsum[3];
  const int slot = off0 + pre + h - 1;
  slot_s[t] = slot;
  if (h) head_s[slot] = t;
  if (t == 0) head_s[k] = CH;   // sentinel
  __syncthreads();

  const int gid = t >> 3, q = t & 7;

  for (int base = 0; base < k; base += CROWS) {
    const int nb = min(CROWS, k - base);
    if (base) __syncthreads();            // protect rows[] from prior readers
    {
      const int s = gid;                  // 32 groups stage up to 32 rows
      if (s < nb) {
        const float* src = &all_items[(size_t)item_s[head_s[base + s]] * Dn + q * 4];
#pragma unroll
        for (int j = 0; j < 8; ++j)
          *(float4*)&rows[s][q * 4 + j * 32] = *(const float4*)&src[j * 32];
      }
    }
    __syncthreads();

    const int lo = head_s[base];
    const int hi = head_s[base + nb];     // sentinel covers base+nb == k
    for (int i = lo + gid; i < hi; i += 32) {
      const int cid = cid_s[i];
      const int sl  = slot_s[i] - base;
      const float* fp = &f[(size_t)(cid >> 8) * Dn + q * 4];
      float4 fv[8];
#pragma unroll
      for (int j = 0; j < 8; ++j) fv[j] = *(const float4*)&fp[j * 32];
      __builtin_amdgcn_sched_barrier(0);  // keep all 8 loads in flight
      float a0 = 0.f, a1 = 0.f;
#pragma unroll
      for (int j = 0; j < 8; j += 2) {
        const float4 r0 = *(const float4*)&rows[sl][q * 4 + j * 32];
        const float4 r1 = *(const float4*)&rows[sl][q * 4 + (j + 1) * 32];
        a0 = fmaf(fv[j].x, r0.x, a0);
        a0 = fmaf(fv[j].y, r0.y, a0);
        a0 = fmaf(fv[j].z, r0.z, a0);
        a0 = fmaf(fv[j].w, r0.w, a0);
        a1 = fmaf(fv[j + 1].x, r1.x, a1);
        a1 = fmaf(fv[j + 1].y, r1.y, a1);
        a1 = fmaf(fv[j + 1].z, r1.z, a1);
        a1 = fmaf(fv[j + 1].w, r1.w, a1);
      }
      float acc = a0 + a1;
      acc += __shfl_xor(acc, 1, 64);
      acc += __shfl_xor(acc, 2, 64);
      acc += __shfl_xor(acc, 4, 64);
      if (q == 0) scores[cid] = acc;
    }
  }
}

// ---------------------------------------------------------------------------
// finish: softmax + weighted index + compacted pass-2 (verified structure)
// ---------------------------------------------------------------------------
__global__ __launch_bounds__(256) void finish_kernel(
    const int* __restrict__ need_replace, const int* __restrict__ user_sample_items,
    const float* __restrict__ scores, const float* __restrict__ all_items,
    float* __restrict__ out_items, float* __restrict__ feat_out,
    float* __restrict__ out_scalars) {
  __shared__ float red_s[8];
  __shared__ int   sel_idx[Sn];
  __shared__ float sel_p[Sn];
  __shared__ int   warp_cnt[4];

  const int b = blockIdx.x, t = threadIdx.x;
  const int lane = t & 63, w = t >> 6;
  const int uid = need_replace[b * 2];
  const int myitem = user_sample_items[(size_t)uid * Sn + t];
  const float v = scores[b * Sn + t];

  float m = v;
#pragma unroll
  for (int off = 32; off; off >>= 1) m = fmaxf(m, __shfl_xor(m, off, 64));
  if (lane == 0) red_s[w] = m;
  __syncthreads();
  m = fmaxf(fmaxf(red_s[0], red_s[1]), fmaxf(red_s[2], red_s[3]));

  const float e0 = expf(v - m);
  float ssum = e0;
#pragma unroll
  for (int off = 32; off; off >>= 1) ssum += __shfl_xor(ssum, off, 64);
  if (lane == 0) red_s[4 + w] = ssum;
  __syncthreads();
  const float tot = red_s[4] + red_s[5] + red_s[6] + red_s[7];
  const float p = e0 / tot;

  float ri = p * (float)myitem;
#pragma unroll
  for (int off = 32; off; off >>= 1) ri += __shfl_xor(ri, off, 64);
  if (lane == 0) red_s[w] = ri;

  const bool flag = (p >= 1e-7f);
  const unsigned long long mask = __ballot(flag);
  const int wc     = __popcll(mask);
  const int prefix = __popcll(mask & ((1ull << lane) - 1ull));
  if (lane == 0) warp_cnt[w] = wc;
  __syncthreads();

  if (t == 0) {
    const float tot_ri = red_s[0] + red_s[1] + red_s[2] + red_s[3];
    out_items[b] = (float)(int)tot_ri;
  }
  int off0 = 0;
  for (int i = 0; i < w; ++i) off0 += warp_cnt[i];
  const int nsel = warp_cnt[0] + warp_cnt[1] + warp_cnt[2] + warp_cnt[3];
  if (flag) {
    sel_idx[off0 + prefix] = myitem;
    sel_p[off0 + prefix]   = p;
  }
  __syncthreads();

  float acc = 0.f;
  for (int i = 0; i < nsel; ++i)
    acc += sel_p[i] * all_items[(size_t)sel_idx[i] * Dn + t];
  feat_out[(size_t)b * Dn + t] = acc;

  if (b == 0 && t < 2) out_scalars[t] = 0.f;
}

// ---------------------------------------------------------------------------
// fold helper + fallback main kernel (round-2, verified) for small ws_size.
// ---------------------------------------------------------------------------
__device__ __forceinline__ float fold(float a, float b, int m, int lane) {
  const float keep = (lane & m) ? b : a;
  const float send = (lane & m) ? a : b;
  return keep + __shfl_xor(send, m, 64);
}

__global__ __launch_bounds__(256) void main_fb(
    const int* __restrict__ need_replace,
    const int* __restrict__ user_sample_items,
    const float* __restrict__ all_items,
    float* __restrict__ out_items, float* __restrict__ feat_io,
    float* __restrict__ out_scalars) {
  __shared__ __align__(16) float f_s[Dn];
  __shared__ int   items_s[Sn];
  __shared__ float red_s[8];
  __shared__ int   sel_idx[Sn];
  __shared__ float sel_p[Sn];
  __shared__ int   warp_cnt[4];

  const int b = blockIdx.x, t = threadIdx.x;
  const int lane = t & 63, w = t >> 6;
  const int uid = need_replace[b * 2];
  items_s[t] = user_sample_items[(size_t)uid * Sn + t];
  f_s[t]     = feat_io[(size_t)b * Dn + t];
  __syncthreads();

  const float4 fr = *(const float4*)&f_s[lane * 4];
  const int base = w * 64;
  float4 e[8];
#pragma unroll
  for (int j = 0; j < 8; ++j)
    e[j] = *(const float4*)&all_items[(size_t)items_s[base + 8 * j] * Dn + lane * 4];
  float grp[8];
#pragma unroll
  for (int c = 0; c < 8; ++c) {
    float p[8];
#pragma unroll
    for (int j = 0; j < 8; ++j) {
      const float4 ev = e[j];
      p[j] = fmaf(fr.x, ev.x, fmaf(fr.y, ev.y, fmaf(fr.z, ev.z, fr.w * ev.w)));
      if (c < 7)
        e[j] = *(const float4*)&all_items[(size_t)items_s[base + (c + 1) + 8 * j] * Dn + lane * 4];
    }
    const float q0 = fold(p[0], p[4], 32, lane), q1 = fold(p[1], p[5], 32, lane);
    const float q2 = fold(p[2], p[6], 32, lane), q3 = fold(p[3], p[7], 32, lane);
    const float r0 = fold(q0, q2, 16, lane),     r1 = fold(q1, q3, 16, lane);
    grp[c] = fold(r0, r1, 8, lane);
  }
  const float s0 = fold(grp[0], grp[4], 4, lane), s1 = fold(grp[1], grp[5], 4, lane);
  const float s2 = fold(grp[2], grp[6], 4, lane), s3 = fold(grp[3], grp[7], 4, lane);
  const float t0 = fold(s0, s2, 2, lane),         t1 = fold(s1, s3, 2, lane);
  const float v  = fold(t0, t1, 1, lane);

  float m = v;
#pragma unroll
  for (int off = 32; off; off >>= 1) m = fmaxf(m, __shfl_xor(m, off, 64));
  if (lane == 0) red_s[w] = m;
  __syncthreads();
  m = fmaxf(fmaxf(red_s[0], red_s[1]), fmaxf(red_s[2], red_s[3]));
  const float e0 = expf(v - m);
  float ssum = e0;
#pragma unroll
  for (int off = 32; off; off >>= 1) ssum += __shfl_xor(ssum, off, 64);
  if (lane == 0) red_s[4 + w] = ssum;
  __syncthreads();
  const float tot = red_s[4] + red_s[5] + red_s[6] + red_s[7];
  const float p = e0 / tot;
  float ri = p * (float)items_s[t];
#pragma unroll
  for (int off = 32; off; off >>= 1) ri += __shfl_xor(ri, off, 64);
  if (lane == 0) red_s[w] = ri;
  const bool flag = (p >= 1e-7f);
  const unsigned long long mask = __ballot(flag);
  const int wc = __popcll(mask);
  const int prefix = __popcll(mask & ((1ull << lane) - 1ull));
  if (lane == 0) warp_cnt[w] = wc;
  __syncthreads();
  if (t == 0) {
    const float tot_ri = red_s[0] + red_s[1] + red_s[2] + red_s[3];
    out_items[b] = (float)(int)tot_ri;
  }
  int off0 = 0;
  for (int i = 0; i < w; ++i) off0 += warp_cnt[i];
  const int nsel = warp_cnt[0] + warp_cnt[1] + warp_cnt[2] + warp_cnt[3];
  if (flag) {
    sel_idx[off0 + prefix] = items_s[t];
    sel_p[off0 + prefix]   = p;
  }
  __syncthreads();
  float acc = 0.f;
  for (int i = 0; i < nsel; ++i)
    acc += sel_p[i] * all_items[(size_t)sel_idx[i] * Dn + t];
  feat_io[(size_t)b * Dn + t] = acc;
  if (b == 0 && t < 2) out_scalars[t] = 0.f;
}

extern "C" void kernel_launch(void* const* d_in, const int* in_sizes, int n_in,
                              void* d_out, int out_size, void* d_ws, size_t ws_size,
                              hipStream_t stream) {
  const int*   need_replace      = (const int*)d_in[0];
  const float* union_feature     = (const float*)d_in[1];
  const float* all_items         = (const float*)d_in[2];
  const float* privacy_settings  = (const float*)d_in[3];
  const int*   user_sample_items = (const int*)d_in[4];
  const float* W                 = (const float*)d_in[5];
  const float* bias              = (const float*)d_in[6];

  float* out       = (float*)d_out;
  float* out_items = out;
  float* feat_io   = out + Bn;                     // f, then feature out
  float* out_scal  = out + Bn + (size_t)Bn * Dn;

  const size_t NEED = (size_t)1048576 * 8          // pairs
                    + (size_t)1048576 * 4          // scores
                    + (size_t)3 * NITEMS * 4 + 512 * 4;
  int2*  pairs    = (int2*)d_ws;
  float* scores   = (float*)(pairs + 1048576);
  int*   cnt      = (int*)(scores + 1048576);
  int*   offsets  = cnt + NITEMS;
  int*   cursor   = offsets + NITEMS;
  int*   blocksum = cursor + NITEMS;

  hipMemsetAsync(feat_io, 0, (size_t)Bn * Dn * sizeof(float), stream);

  if (ws_size >= NEED) {
    hipMemsetAsync(cnt, 0, NITEMS * sizeof(int), stream);
    feat_hist<<<512, 256, 0, stream>>>(union_feature, privacy_settings, W, bias,
                                       need_replace, user_sample_items,
                                       feat_io, cnt);
    scan_a<<<NBLK_SCAN, 256, 0, stream>>>(cnt, offsets, blocksum);
    scan_bc<<<NBLK_SCAN, 256, 0, stream>>>(blocksum, offsets, cursor);
    scatter_kernel<<<Bn, 256, 0, stream>>>(need_replace, user_sample_items,
                                           cursor, pairs);
    score_runs<<<Bn, 256, 0, stream>>>(all_items, feat_io, pairs, scores);
    finish_kernel<<<Bn, 256, 0, stream>>>(need_replace, user_sample_items, scores,
                                          all_items, out_items, feat_io, out_scal);
  } else {
    feat_hist<<<512, 256, 0, stream>>>(union_feature, privacy_settings, W, bias,
                                       need_replace, user_sample_items,
                                       feat_io, nullptr);
    main_fb<<<Bn, 256, 0, stream>>>(need_replace, user_sample_items, all_items,
                                    out_items, feat_io, out_scal);
  }
}

// Round 8
// 243.184 us; speedup vs baseline: 1.0429x; 1.0429x over previous
//
#include <hip/hip_runtime.h>

constexpr int Bn = 4096;
constexpr int Dn = 256;
constexpr int Sn = 256;
constexpr int NITEMS = 100000;
constexpr int NBLK_SCAN = (NITEMS + 255) / 256;   // 391

// ---------------------------------------------------------------------------
// feat_hist (R6 verified): f = uf_cat @ W^T + bias (64x64 tile, 4x4 micro,
// BK=32, grid 256) + fused item-usage histogram (cnt pre-zeroed by memset).
// ---------------------------------------------------------------------------
__global__ __launch_bounds__(256) void feat_hist(
    const float* __restrict__ uf, const float* __restrict__ priv,
    const float* __restrict__ W,  const float* __restrict__ bias,
    const int* __restrict__ need_replace, const int* __restrict__ user_sample_items,
    float* __restrict__ fout, int* __restrict__ cnt) {
  __shared__ float A_s[32][68];
  __shared__ float B_s[32][68];
  const int t = threadIdx.x;

  if (cnt != nullptr) {
#pragma unroll
    for (int it = 0; it < 16; ++it) {
      const int b = blockIdx.x * 16 + it;
      const int uid  = need_replace[b * 2];
      const int item = user_sample_items[(size_t)uid * Sn + t];
      atomicAdd(&cnt[item], 1);
    }
  }

  const int m0 = (blockIdx.x >> 2) * 64;
  const int n0 = (blockIdx.x & 3) * 64;
  const int tx = t & 15, ty = t >> 4;

  float acc[4][4];
#pragma unroll
  for (int i = 0; i < 4; ++i)
#pragma unroll
    for (int j = 0; j < 4; ++j) acc[i][j] = 0.f;

  float ra[8], rb[8];
#pragma unroll
  for (int p = 0; p < 8; ++p) {
    const int e = t + p * 256, kk = e & 31, m = e >> 5;
    ra[p] = uf[(size_t)(m0 + m) * 512 + kk];
    rb[p] = W[(size_t)(n0 + m) * 513 + kk];
  }

  for (int c = 0; c < 16; ++c) {
#pragma unroll
    for (int p = 0; p < 8; ++p) {
      const int e = t + p * 256, kk = e & 31, m = e >> 5;
      A_s[kk][m] = ra[p];
      B_s[kk][m] = rb[p];
    }
    __syncthreads();
    if (c < 15) {
      const int k0 = (c + 1) * 32;
#pragma unroll
      for (int p = 0; p < 8; ++p) {
        const int e = t + p * 256, kk = e & 31, m = e >> 5;
        ra[p] = uf[(size_t)(m0 + m) * 512 + k0 + kk];
        rb[p] = W[(size_t)(n0 + m) * 513 + k0 + kk];
      }
    }
#pragma unroll
    for (int kk = 0; kk < 32; ++kk) {
      const float4 a4 = *(const float4*)&A_s[kk][ty * 4];
      const float4 b4 = *(const float4*)&B_s[kk][tx * 4];
      const float av[4] = {a4.x, a4.y, a4.z, a4.w};
      const float bv[4] = {b4.x, b4.y, b4.z, b4.w};
#pragma unroll
      for (int i = 0; i < 4; ++i)
#pragma unroll
        for (int j = 0; j < 4; ++j) acc[i][j] = fmaf(av[i], bv[j], acc[i][j]);
    }
    __syncthreads();
  }

  float av[4], bv[4];
#pragma unroll
  for (int i = 0; i < 4; ++i) av[i] = priv[m0 + ty * 4 + i];
#pragma unroll
  for (int j = 0; j < 4; ++j) bv[j] = W[(size_t)(n0 + tx * 4 + j) * 513 + 512];
#pragma unroll
  for (int i = 0; i < 4; ++i)
#pragma unroll
    for (int j = 0; j < 4; ++j) acc[i][j] = fmaf(av[i], bv[j], acc[i][j]);

  const float4 bb = *(const float4*)&bias[n0 + tx * 4];
#pragma unroll
  for (int i = 0; i < 4; ++i) {
    float4 o;
    o.x = acc[i][0] + bb.x; o.y = acc[i][1] + bb.y;
    o.z = acc[i][2] + bb.z; o.w = acc[i][3] + bb.w;
    *(float4*)&fout[(size_t)(m0 + ty * 4 + i) * Dn + n0 + tx * 4] = o;
  }
}

// ---------------------------------------------------------------------------
// scan_a: block-local exclusive scan of cnt + per-block sums
// ---------------------------------------------------------------------------
__global__ __launch_bounds__(256) void scan_a(const int* __restrict__ cnt,
                                              int* __restrict__ offsets,
                                              int* __restrict__ blocksum) {
  __shared__ int s[256];
  const int tid = threadIdx.x;
  const int i = blockIdx.x * 256 + tid;
  const int v = (i < NITEMS) ? cnt[i] : 0;
  int x = v;
  s[tid] = x;
  __syncthreads();
  for (int d = 1; d < 256; d <<= 1) {
    const int add = (tid >= d) ? s[tid - d] : 0;
    __syncthreads();
    x += add;
    s[tid] = x;
    __syncthreads();
  }
  if (i < NITEMS) offsets[i] = x - v;
  if (tid == 255) blocksum[blockIdx.x] = x;
}

// ---------------------------------------------------------------------------
// scan_bc: block j sums blocksum[0..j) itself, finalizes offsets + cursor.
// ---------------------------------------------------------------------------
__global__ __launch_bounds__(256) void scan_bc(const int* __restrict__ blocksum,
                                               int* __restrict__ offsets,
                                               int* __restrict__ cursor) {
  __shared__ int red[4];
  const int tid = threadIdx.x, lane = tid & 63, w = tid >> 6;
  const int j = blockIdx.x;
  int part = 0;
  for (int i = tid; i < j; i += 256) part += blocksum[i];
#pragma unroll
  for (int off = 32; off; off >>= 1) part += __shfl_xor(part, off, 64);
  if (lane == 0) red[w] = part;
  __syncthreads();
  const int prefix = red[0] + red[1] + red[2] + red[3];
  const int i = j * 256 + tid;
  if (i < NITEMS) {
    const int o = offsets[i] + prefix;
    offsets[i] = o;
    cursor[i]  = o;
  }
}

// ---------------------------------------------------------------------------
// scatter: emit (cid, item) pairs grouped by item
// ---------------------------------------------------------------------------
__global__ __launch_bounds__(256) void scatter_kernel(
    const int* __restrict__ need_replace, const int* __restrict__ user_sample_items,
    int* __restrict__ cursor, int2* __restrict__ pairs) {
  const int b = blockIdx.x, t = threadIdx.x;
  const int uid  = need_replace[b * 2];
  const int item = user_sample_items[(size_t)uid * Sn + t];
  const int pos  = atomicAdd(&cursor[item], 1);
  pairs[pos] = make_int2(b * Sn + t, item);
}

// ---------------------------------------------------------------------------
// score_runs2: 2048 blocks x 512 thr; block owns 512 item-sorted pairs.
// Distinct item rows staged once in LDS (CROWS=64, ~75 KB -> 2 blocks/CU).
// 8-lane group per pair, 2-deep software pipeline on the f-row loads:
// pair i+64's 8x16B loads are issued before pair i's FMAs, hiding L2
// latency under compute. Deterministic: score = g(cid,item) only.
// ---------------------------------------------------------------------------
constexpr int CH    = 512;
constexpr int CROWS = 64;
constexpr int RP    = Dn + 4;

__global__ __launch_bounds__(512, 4) void score_runs2(
    const float* __restrict__ all_items, const float* __restrict__ f,
    const int2* __restrict__ pairs, float* __restrict__ scores) {
  __shared__ float rows[CROWS][RP];
  __shared__ int cid_s[CH];
  __shared__ int item_s[CH];
  __shared__ int slot_s[CH];
  __shared__ int head_s[CH + 1];
  __shared__ int wsum[8];

  const int t = threadIdx.x, lane = t & 63, w = t >> 6;

  const int2 pr = pairs[(size_t)blockIdx.x * CH + t];
  cid_s[t]  = pr.x;
  item_s[t] = pr.y;
  __syncthreads();

  const int h = (t == 0) ? 1 : (item_s[t] != item_s[t - 1] ? 1 : 0);
  const unsigned long long mask = __ballot(h != 0);
  const int wc  = __popcll(mask);
  const int pre = __popcll(mask & ((1ull << lane) - 1ull));
  if (lane == 0) wsum[w] = wc;
  __syncthreads();
  int off0 = 0;
  for (int i = 0; i < w; ++i) off0 += wsum[i];
  int k = 0;
#pragma unroll
  for (int i = 0; i < 8; ++i) k += wsum[i];
  const int slot = off0 + pre + h - 1;
  slot_s[t] = slot;
  if (h) head_s[slot] = t;
  if (t == 0) head_s[k] = CH;   // sentinel
  __syncthreads();

  const int gid = t >> 3, q = t & 7;

  for (int base = 0; base < k; base += CROWS) {
    const int nb = min(CROWS, k - base);
    if (base) __syncthreads();            // protect rows[] from prior readers
    if (gid < nb) {                       // 64 groups stage up to 64 rows
      const float* src = &all_items[(size_t)item_s[head_s[base + gid]] * Dn + q * 4];
#pragma unroll
      for (int j = 0; j < 8; ++j)
        *(float4*)&rows[gid][q * 4 + j * 32] = *(const float4*)&src[j * 32];
    }
    __syncthreads();

    const int lo = head_s[base];
    const int hi = head_s[base + nb];     // sentinel covers base+nb == k
    int i = lo + gid;
    if (i < hi) {
      float4 fv[8];
      {
        const float* fp = &f[(size_t)(cid_s[i] >> 8) * Dn + q * 4];
#pragma unroll
        for (int j = 0; j < 8; ++j) fv[j] = *(const float4*)&fp[j * 32];
      }
      while (i < hi) {
        const int inext = i + 64;
        float4 fw[8];
        if (inext < hi) {
          const float* fp = &f[(size_t)(cid_s[inext] >> 8) * Dn + q * 4];
#pragma unroll
          for (int j = 0; j < 8; ++j) fw[j] = *(const float4*)&fp[j * 32];
        }
        const int cid = cid_s[i];
        const int sl  = slot_s[i] - base;
        float a0 = 0.f, a1 = 0.f;
#pragma unroll
        for (int j = 0; j < 8; j += 2) {
          const float4 r0 = *(const float4*)&rows[sl][q * 4 + j * 32];
          const float4 r1 = *(const float4*)&rows[sl][q * 4 + (j + 1) * 32];
          a0 = fmaf(fv[j].x, r0.x, a0);
          a0 = fmaf(fv[j].y, r0.y, a0);
          a0 = fmaf(fv[j].z, r0.z, a0);
          a0 = fmaf(fv[j].w, r0.w, a0);
          a1 = fmaf(fv[j + 1].x, r1.x, a1);
          a1 = fmaf(fv[j + 1].y, r1.y, a1);
          a1 = fmaf(fv[j + 1].z, r1.z, a1);
          a1 = fmaf(fv[j + 1].w, r1.w, a1);
        }
        float acc = a0 + a1;
        acc += __shfl_xor(acc, 1, 64);
        acc += __shfl_xor(acc, 2, 64);
        acc += __shfl_xor(acc, 4, 64);
        if (q == 0) scores[cid] = acc;
        i = inext;
#pragma unroll
        for (int j = 0; j < 8; ++j) fv[j] = fw[j];
      }
    }
  }
}

// ---------------------------------------------------------------------------
// finish: softmax + weighted index + compacted pass-2 (verified structure)
// ---------------------------------------------------------------------------
__global__ __launch_bounds__(256) void finish_kernel(
    const int* __restrict__ need_replace, const int* __restrict__ user_sample_items,
    const float* __restrict__ scores, const float* __restrict__ all_items,
    float* __restrict__ out_items, float* __restrict__ feat_out,
    float* __restrict__ out_scalars) {
  __shared__ float red_s[8];
  __shared__ int   sel_idx[Sn];
  __shared__ float sel_p[Sn];
  __shared__ int   warp_cnt[4];

  const int b = blockIdx.x, t = threadIdx.x;
  const int lane = t & 63, w = t >> 6;
  const int uid = need_replace[b * 2];
  const int myitem = user_sample_items[(size_t)uid * Sn + t];
  const float v = scores[b * Sn + t];

  float m = v;
#pragma unroll
  for (int off = 32; off; off >>= 1) m = fmaxf(m, __shfl_xor(m, off, 64));
  if (lane == 0) red_s[w] = m;
  __syncthreads();
  m = fmaxf(fmaxf(red_s[0], red_s[1]), fmaxf(red_s[2], red_s[3]));

  const float e0 = expf(v - m);
  float ssum = e0;
#pragma unroll
  for (int off = 32; off; off >>= 1) ssum += __shfl_xor(ssum, off, 64);
  if (lane == 0) red_s[4 + w] = ssum;
  __syncthreads();
  const float tot = red_s[4] + red_s[5] + red_s[6] + red_s[7];
  const float p = e0 / tot;

  float ri = p * (float)myitem;
#pragma unroll
  for (int off = 32; off; off >>= 1) ri += __shfl_xor(ri, off, 64);
  if (lane == 0) red_s[w] = ri;

  const bool flag = (p >= 1e-7f);
  const unsigned long long mask = __ballot(flag);
  const int wc     = __popcll(mask);
  const int prefix = __popcll(mask & ((1ull << lane) - 1ull));
  if (lane == 0) warp_cnt[w] = wc;
  __syncthreads();

  if (t == 0) {
    const float tot_ri = red_s[0] + red_s[1] + red_s[2] + red_s[3];
    out_items[b] = (float)(int)tot_ri;
  }
  int off0 = 0;
  for (int i = 0; i < w; ++i) off0 += warp_cnt[i];
  const int nsel = warp_cnt[0] + warp_cnt[1] + warp_cnt[2] + warp_cnt[3];
  if (flag) {
    sel_idx[off0 + prefix] = myitem;
    sel_p[off0 + prefix]   = p;
  }
  __syncthreads();

  float acc = 0.f;
  for (int i = 0; i < nsel; ++i)
    acc += sel_p[i] * all_items[(size_t)sel_idx[i] * Dn + t];
  feat_out[(size_t)b * Dn + t] = acc;

  if (b == 0 && t < 2) out_scalars[t] = 0.f;
}

// ---------------------------------------------------------------------------
// fold helper + fallback main kernel (round-2, verified) for small ws_size.
// ---------------------------------------------------------------------------
__device__ __forceinline__ float fold(float a, float b, int m, int lane) {
  const float keep = (lane & m) ? b : a;
  const float send = (lane & m) ? a : b;
  return keep + __shfl_xor(send, m, 64);
}

__global__ __launch_bounds__(256) void main_fb(
    const int* __restrict__ need_replace,
    const int* __restrict__ user_sample_items,
    const float* __restrict__ all_items,
    float* __restrict__ out_items, float* __restrict__ feat_io,
    float* __restrict__ out_scalars) {
  __shared__ __align__(16) float f_s[Dn];
  __shared__ int   items_s[Sn];
  __shared__ float red_s[8];
  __shared__ int   sel_idx[Sn];
  __shared__ float sel_p[Sn];
  __shared__ int   warp_cnt[4];

  const int b = blockIdx.x, t = threadIdx.x;
  const int lane = t & 63, w = t >> 6;
  const int uid = need_replace[b * 2];
  items_s[t] = user_sample_items[(size_t)uid * Sn + t];
  f_s[t]     = feat_io[(size_t)b * Dn + t];
  __syncthreads();

  const float4 fr = *(const float4*)&f_s[lane * 4];
  const int base = w * 64;
  float4 e[8];
#pragma unroll
  for (int j = 0; j < 8; ++j)
    e[j] = *(const float4*)&all_items[(size_t)items_s[base + 8 * j] * Dn + lane * 4];
  float grp[8];
#pragma unroll
  for (int c = 0; c < 8; ++c) {
    float p[8];
#pragma unroll
    for (int j = 0; j < 8; ++j) {
      const float4 ev = e[j];
      p[j] = fmaf(fr.x, ev.x, fmaf(fr.y, ev.y, fmaf(fr.z, ev.z, fr.w * ev.w)));
      if (c < 7)
        e[j] = *(const float4*)&all_items[(size_t)items_s[base + (c + 1) + 8 * j] * Dn + lane * 4];
    }
    const float q0 = fold(p[0], p[4], 32, lane), q1 = fold(p[1], p[5], 32, lane);
    const float q2 = fold(p[2], p[6], 32, lane), q3 = fold(p[3], p[7], 32, lane);
    const float r0 = fold(q0, q2, 16, lane),     r1 = fold(q1, q3, 16, lane);
    grp[c] = fold(r0, r1, 8, lane);
  }
  const float s0 = fold(grp[0], grp[4], 4, lane), s1 = fold(grp[1], grp[5], 4, lane);
  const float s2 = fold(grp[2], grp[6], 4, lane), s3 = fold(grp[3], grp[7], 4, lane);
  const float t0 = fold(s0, s2, 2, lane),         t1 = fold(s1, s3, 2, lane);
  const float v  = fold(t0, t1, 1, lane);

  float m = v;
#pragma unroll
  for (int off = 32; off; off >>= 1) m = fmaxf(m, __shfl_xor(m, off, 64));
  if (lane == 0) red_s[w] = m;
  __syncthreads();
  m = fmaxf(fmaxf(red_s[0], red_s[1]), fmaxf(red_s[2], red_s[3]));
  const float e0 = expf(v - m);
  float ssum = e0;
#pragma unroll
  for (int off = 32; off; off >>= 1) ssum += __shfl_xor(ssum, off, 64);
  if (lane == 0) red_s[4 + w] = ssum;
  __syncthreads();
  const float tot = red_s[4] + red_s[5] + red_s[6] + red_s[7];
  const float p = e0 / tot;
  float ri = p * (float)items_s[t];
#pragma unroll
  for (int off = 32; off; off >>= 1) ri += __shfl_xor(ri, off, 64);
  if (lane == 0) red_s[w] = ri;
  const bool flag = (p >= 1e-7f);
  const unsigned long long mask = __ballot(flag);
  const int wc = __popcll(mask);
  const int prefix = __popcll(mask & ((1ull << lane) - 1ull));
  if (lane == 0) warp_cnt[w] = wc;
  __syncthreads();
  if (t == 0) {
    const float tot_ri = red_s[0] + red_s[1] + red_s[2] + red_s[3];
    out_items[b] = (float)(int)tot_ri;
  }
  int off0 = 0;
  for (int i = 0; i < w; ++i) off0 += warp_cnt[i];
  const int nsel = warp_cnt[0] + warp_cnt[1] + warp_cnt[2] + warp_cnt[3];
  if (flag) {
    sel_idx[off0 + prefix] = items_s[t];
    sel_p[off0 + prefix]   = p;
  }
  __syncthreads();
  float acc = 0.f;
  for (int i = 0; i < nsel; ++i)
    acc += sel_p[i] * all_items[(size_t)sel_idx[i] * Dn + t];
  feat_io[(size_t)b * Dn + t] = acc;
  if (b == 0 && t < 2) out_scalars[t] = 0.f;
}

extern "C" void kernel_launch(void* const* d_in, const int* in_sizes, int n_in,
                              void* d_out, int out_size, void* d_ws, size_t ws_size,
                              hipStream_t stream) {
  const int*   need_replace      = (const int*)d_in[0];
  const float* union_feature     = (const float*)d_in[1];
  const float* all_items         = (const float*)d_in[2];
  const float* privacy_settings  = (const float*)d_in[3];
  const int*   user_sample_items = (const int*)d_in[4];
  const float* W                 = (const float*)d_in[5];
  const float* bias              = (const float*)d_in[6];

  float* out       = (float*)d_out;
  float* out_items = out;
  float* feat_io   = out + Bn;                     // f, then feature out
  float* out_scal  = out + Bn + (size_t)Bn * Dn;

  const size_t NEED = (size_t)1048576 * 8          // pairs
                    + (size_t)1048576 * 4          // scores
                    + (size_t)3 * NITEMS * 4 + 512 * 4;
  int2*  pairs    = (int2*)d_ws;
  float* scores   = (float*)(pairs + 1048576);
  int*   cnt      = (int*)(scores + 1048576);
  int*   offsets  = cnt + NITEMS;
  int*   cursor   = offsets + NITEMS;
  int*   blocksum = cursor + NITEMS;

  if (ws_size >= NEED) {
    hipMemsetAsync(cnt, 0, NITEMS * sizeof(int), stream);
    feat_hist<<<256, 256, 0, stream>>>(union_feature, privacy_settings, W, bias,
                                       need_replace, user_sample_items,
                                       feat_io, cnt);
    scan_a<<<NBLK_SCAN, 256, 0, stream>>>(cnt, offsets, blocksum);
    scan_bc<<<NBLK_SCAN, 256, 0, stream>>>(blocksum, offsets, cursor);
    scatter_kernel<<<Bn, 256, 0, stream>>>(need_replace, user_sample_items,
                                           cursor, pairs);
    score_runs2<<<1048576 / CH, 512, 0, stream>>>(all_items, feat_io, pairs, scores);
    finish_kernel<<<Bn, 256, 0, stream>>>(need_replace, user_sample_items, scores,
                                          all_items, out_items, feat_io, out_scal);
  } else {
    feat_hist<<<256, 256, 0, stream>>>(union_feature, privacy_settings, W, bias,
                                       need_replace, user_sample_items,
                                       feat_io, nullptr);
    main_fb<<<Bn, 256, 0, stream>>>(need_replace, user_sample_items, all_items,
                                    out_items, feat_io, out_scal);
  }
}